// Round 1
// baseline (1396.631 us; speedup 1.0000x reference)
//
#include <hip/hip_runtime.h>
#include <math.h>

#define T_STEPS 5
#define BATCH 32

// ---------------------------------------------------------------------------
// Tiled 5x5 VALID conv, fp32, NCHW. Block = (32,8): threadIdx.x = output row
// within 32x32 tile, threadIdx.y = group of 4 consecutive output cols.
// LDS stages a 36x36 input patch (rows padded to 40 floats -> 16B-aligned
// float4 reads, even bank spread). Weights read via block-uniform addresses
// (co,ci uniform) -> scalar loads. Register sliding window: per (ci,kh) read
// 8 contiguous floats (2x float4), do 20 FMAs.
// ---------------------------------------------------------------------------
template <int CIN>
__global__ __launch_bounds__(256) void conv5_tiled(
    const float* __restrict__ in, const float* __restrict__ wgt,
    float* __restrict__ out, int Hin, int Win, int Hout, int Wout,
    int tiles_w) {
  __shared__ __align__(16) float lds[36 * 40];
  const int ry = threadIdx.x;              // 0..31 row in tile
  const int cx = threadIdx.y;              // 0..7  col-group (4 cols each)
  const int tid = threadIdx.y * 32 + threadIdx.x;
  const int Cout = gridDim.y;
  const int co = blockIdx.y;
  const int n = blockIdx.z;
  const int th = blockIdx.x / tiles_w;
  const int tw = blockIdx.x - th * tiles_w;
  const int ho0 = th * 32, wo0 = tw * 32;

  float acc0 = 0.f, acc1 = 0.f, acc2 = 0.f, acc3 = 0.f;
  const float4* l4 = reinterpret_cast<const float4*>(lds);

  for (int ci = 0; ci < CIN; ++ci) {
    // stage 36x36 patch
    const float* ip = in + ((n * CIN + ci) * Hin) * Win;
    for (int idx = tid; idx < 36 * 36; idx += 256) {
      int r = idx / 36;
      int c = idx - r * 36;
      int gr = ho0 + r, gc = wo0 + c;
      float v = 0.f;
      if (gr < Hin && gc < Win) v = ip[gr * Win + gc];
      lds[r * 40 + c] = v;
    }
    __syncthreads();
    const float* wp = wgt + (co * CIN + ci) * 25;
#pragma unroll
    for (int kh = 0; kh < 5; ++kh) {
      float4 A = l4[(ry + kh) * 10 + cx];
      float4 Bv = l4[(ry + kh) * 10 + cx + 1];
      float v[8] = {A.x, A.y, A.z, A.w, Bv.x, Bv.y, Bv.z, Bv.w};
#pragma unroll
      for (int kw = 0; kw < 5; ++kw) {
        float w = wp[kh * 5 + kw];
        acc0 += v[kw + 0] * w;
        acc1 += v[kw + 1] * w;
        acc2 += v[kw + 2] * w;
        acc3 += v[kw + 3] * w;
      }
    }
    __syncthreads();
  }

  const int ho = ho0 + ry;
  if (ho < Hout) {
    float* op = out + ((n * Cout + co) * Hout + ho) * Wout;
    int w0 = wo0 + cx * 4;
    if (w0 + 0 < Wout) op[w0 + 0] = acc0;
    if (w0 + 1 < Wout) op[w0 + 1] = acc1;
    if (w0 + 2 < Wout) op[w0 + 2] = acc2;
    if (w0 + 3 < Wout) op[w0 + 3] = acc3;
  }
}

// Simple direct conv (used for conv4: 8x8 outputs, small) -------------------
__global__ __launch_bounds__(256) void conv5_simple(
    const float* __restrict__ in, const float* __restrict__ wgt,
    float* __restrict__ out, int N, int Cin, int Cout, int Hin, int Win,
    int Hout, int Wout) {
  int idx = blockIdx.x * 256 + threadIdx.x;
  int total = N * Cout * Hout * Wout;
  if (idx >= total) return;
  int wo = idx % Wout;
  int t = idx / Wout;
  int ho = t % Hout;
  t /= Hout;
  int co = t % Cout;
  int n = t / Cout;
  float acc = 0.f;
  for (int ci = 0; ci < Cin; ++ci) {
    const float* ip = in + ((n * Cin + ci) * Hin + ho) * Win + wo;
    const float* wp = wgt + (co * Cin + ci) * 25;
#pragma unroll
    for (int kh = 0; kh < 5; ++kh)
#pragma unroll
      for (int kw = 0; kw < 5; ++kw) acc += ip[kh * Win + kw] * wp[kh * 5 + kw];
  }
  out[idx] = acc;
}

// BN stats: two-stage deterministic partial sums in double ------------------
__global__ __launch_bounds__(256) void bn_partial(
    const float* __restrict__ y, int C, int M, int HW, double inv_hw,
    double* __restrict__ psum, double* __restrict__ psq, int S) {
  const int c = blockIdx.x / S;
  const int s = blockIdx.x - c * S;
  const int tid = threadIdx.x;
  double sum = 0.0, sumsq = 0.0;
  for (int i = s * 256 + tid; i < M; i += S * 256) {
    int n = (int)((double)i * inv_hw);
    int hw = i - n * HW;
    if (hw < 0) { n--; hw += HW; }
    else if (hw >= HW) { n++; hw -= HW; }
    float v = y[((long)n * C + c) * (long)HW + hw];
    sum += (double)v;
    sumsq += (double)v * (double)v;
  }
  __shared__ double ls[256], ls2[256];
  ls[tid] = sum;
  ls2[tid] = sumsq;
  __syncthreads();
  for (int off = 128; off > 0; off >>= 1) {
    if (tid < off) {
      ls[tid] += ls[tid + off];
      ls2[tid] += ls2[tid + off];
    }
    __syncthreads();
  }
  if (tid == 0) {
    psum[blockIdx.x] = ls[0];
    psq[blockIdx.x] = ls2[0];
  }
}

__global__ void bn_finalize(const double* __restrict__ psum,
                            const double* __restrict__ psq,
                            const float* __restrict__ gamma,
                            const float* __restrict__ beta,
                            float* __restrict__ scale,
                            float* __restrict__ shift, int C, int S,
                            double invM) {
  int c = threadIdx.x;
  if (c >= C) return;
  double s = 0.0, s2 = 0.0;
  for (int i = 0; i < S; ++i) {
    s += psum[c * S + i];
    s2 += psq[c * S + i];
  }
  double m = s * invM;
  double var = s2 * invM - m * m;
  double r = 1.0 / sqrt(var + 1e-5);
  double sc = (double)gamma[c] * r;
  scale[c] = (float)sc;
  shift[c] = (float)((double)beta[c] - m * sc);
}

// Fused BN-affine + 5-step PLIF + 2x2 maxpool -------------------------------
// y layout (Nimg, C, H, W); t_stride = 0 for layer1 (shared conv across t),
// else B*C*H*W. p layout (T, B, C, PH, PW) with spikes as fp32 {0,1}.
__global__ __launch_bounds__(256) void plif_pool(
    const float* __restrict__ y, const float* __restrict__ scale,
    const float* __restrict__ shift, const float* __restrict__ wlif,
    float* __restrict__ p, int C, int H, int W, int PH, int PW,
    long t_stride) {
  int idx = blockIdx.x * 256 + threadIdx.x;
  int total = BATCH * C * PH * PW;
  if (idx >= total) return;
  int pw = idx % PW;
  int t2 = idx / PW;
  int ph = t2 % PH;
  t2 /= PH;
  int c = t2 % C;
  int b = t2 / C;
  const float sc = scale[c], sh = shift[c];
  const float decay = 1.f / (1.f + expf(-wlif[0]));
  const long base = (((long)b * C + c) * H + 2 * ph) * W + 2 * pw;
  const long pbase = (((long)b * C + c) * PH + ph) * PW + pw;
  const long pstr = (long)BATCH * C * PH * PW;
  float v0 = 0.f, v1 = 0.f, v2 = 0.f, v3 = 0.f;
#pragma unroll
  for (int t = 0; t < T_STEPS; ++t) {
    const float* yp = y + t * t_stride + base;
    float x0 = yp[0] * sc + sh;
    float x1 = yp[1] * sc + sh;
    float x2 = yp[W] * sc + sh;
    float x3 = yp[W + 1] * sc + sh;
    v0 += (x0 - v0) * decay;
    v1 += (x1 - v1) * decay;
    v2 += (x2 - v2) * decay;
    v3 += (x3 - v3) * decay;
    float s0 = (v0 >= 1.f) ? 1.f : 0.f;
    float s1 = (v1 >= 1.f) ? 1.f : 0.f;
    float s2 = (v2 >= 1.f) ? 1.f : 0.f;
    float s3 = (v3 >= 1.f) ? 1.f : 0.f;
    v0 = (v0 >= 1.f) ? 0.f : v0;
    v1 = (v1 >= 1.f) ? 0.f : v1;
    v2 = (v2 >= 1.f) ? 0.f : v2;
    v3 = (v3 >= 1.f) ? 0.f : v3;
    p[t * pstr + pbase] = fmaxf(fmaxf(s0, s1), fmaxf(s2, s3));
  }
}

// FC: out[n,o] = dot(x[n,:], w[o,:]) (bias added in PLIF). n block-uniform. --
__global__ __launch_bounds__(256) void fc_kernel(const float* __restrict__ x,
                                                 const float* __restrict__ w,
                                                 float* __restrict__ out,
                                                 int K, int O, int obpn) {
  int n = blockIdx.x / obpn;
  int o = (blockIdx.x - n * obpn) * 256 + threadIdx.x;
  if (o >= O) return;
  const float4* xr = reinterpret_cast<const float4*>(x + (long)n * K);
  const float4* wr = reinterpret_cast<const float4*>(w + (long)o * K);
  float acc = 0.f;
  for (int k = 0; k < K / 4; ++k) {
    float4 a = xr[k];
    float4 b = wr[k];
    acc += a.x * b.x + a.y * b.y + a.z * b.z + a.w * b.w;
  }
  out[(long)n * O + o] = acc;
}

// PLIF over time for FC activations (adds bias), writes spike seq -----------
__global__ __launch_bounds__(256) void plif_fc(const float* __restrict__ h,
                                               const float* __restrict__ bias,
                                               const float* __restrict__ wlif,
                                               float* __restrict__ s_out,
                                               int F) {
  int idx = blockIdx.x * 256 + threadIdx.x;
  if (idx >= BATCH * F) return;
  int f = idx % F;
  int b = idx / F;
  const float decay = 1.f / (1.f + expf(-wlif[0]));
  const float bi = bias[f];
  float v = 0.f;
#pragma unroll
  for (int t = 0; t < T_STEPS; ++t) {
    long off = ((long)(t * BATCH + b)) * F + f;
    float x = h[off] + bi;
    v += (x - v) * decay;
    float s = (v >= 1.f) ? 1.f : 0.f;
    v = (v >= 1.f) ? 0.f : v;
    s_out[off] = s;
  }
}

// Final PLIF + mean over T --------------------------------------------------
__global__ __launch_bounds__(256) void plif_mean(const float* __restrict__ h,
                                                 const float* __restrict__ bias,
                                                 const float* __restrict__ wlif,
                                                 float* __restrict__ out,
                                                 int O) {
  int idx = blockIdx.x * 256 + threadIdx.x;
  if (idx >= BATCH * O) return;
  int o = idx % O;
  int b = idx / O;
  const float decay = 1.f / (1.f + expf(-wlif[0]));
  const float bi = bias[o];
  float v = 0.f, sum = 0.f;
#pragma unroll
  for (int t = 0; t < T_STEPS; ++t) {
    float x = h[(long)(t * BATCH + b) * O + o] + bi;
    v += (x - v) * decay;
    float s = (v >= 1.f) ? 1.f : 0.f;
    v = (v >= 1.f) ? 0.f : v;
    sum += s;
  }
  out[(long)b * O + o] = sum / 5.0f;
}

// ---------------------------------------------------------------------------
extern "C" void kernel_launch(void* const* d_in, const int* in_sizes, int n_in,
                              void* d_out, int out_size, void* d_ws,
                              size_t ws_size, hipStream_t stream) {
  const float* x = (const float*)d_in[0];
  const float* wc1 = (const float*)d_in[1];
  const float* wc2 = (const float*)d_in[2];
  const float* wc3 = (const float*)d_in[3];
  const float* wc4 = (const float*)d_in[4];
  const float* g1 = (const float*)d_in[5];
  const float* b1 = (const float*)d_in[6];
  const float* g2 = (const float*)d_in[7];
  const float* b2 = (const float*)d_in[8];
  const float* g3 = (const float*)d_in[9];
  const float* b3 = (const float*)d_in[10];
  const float* g4 = (const float*)d_in[11];
  const float* b4 = (const float*)d_in[12];
  const float* wl1 = (const float*)d_in[13];
  const float* wl2 = (const float*)d_in[14];
  const float* wl3 = (const float*)d_in[15];
  const float* wl4 = (const float*)d_in[16];
  const float* wl5 = (const float*)d_in[17];
  const float* wl6 = (const float*)d_in[18];
  const float* fc1w = (const float*)d_in[19];
  const float* fc1b = (const float*)d_in[20];
  const float* fc2w = (const float*)d_in[21];
  const float* fc2b = (const float*)d_in[22];
  float* out = (float*)d_out;

  // workspace layout: Y region (max 68,894,720 B) | P region (39,362,560 B)
  // | stats (psum/psq doubles 64*32 each, scale/shift floats)
  char* ws = (char*)d_ws;
  float* Y = (float*)ws;
  float* P = (float*)(ws + 68894720);
  char* Sb = ws + 68894720 + 39362560;
  double* psum = (double*)Sb;
  double* psq = psum + 64 * 32;
  float* scale = (float*)(psq + 64 * 32);
  float* shift = scale + 64;

  const int S = 32;  // partial blocks per channel

  // ---- block 1: conv1 on B=32 only (input replicated over T) ----
  // (32,3,128,128) -> y1 (32,16,124,124)
  conv5_tiled<3><<<dim3(16, 16, 32), dim3(32, 8), 0, stream>>>(
      x, wc1, Y, 128, 128, 124, 124, 4);
  {
    int HW = 124 * 124, M = 32 * HW;
    bn_partial<<<16 * S, 256, 0, stream>>>(Y, 16, M, HW, 1.0 / HW, psum, psq, S);
    bn_finalize<<<1, 64, 0, stream>>>(psum, psq, g1, b1, scale, shift, 16, S,
                                      1.0 / (double)M);
  }
  // PLIF+pool -> p1 (5,32,16,62,62)
  {
    int total = BATCH * 16 * 62 * 62;
    plif_pool<<<(total + 255) / 256, 256, 0, stream>>>(
        Y, scale, shift, wl1, P, 16, 124, 124, 62, 62, 0L);
  }

  // ---- block 2: conv2 (160,16,62,62) -> y2 (160,32,58,58) ----
  conv5_tiled<16><<<dim3(4, 32, 160), dim3(32, 8), 0, stream>>>(
      P, wc2, Y, 62, 62, 58, 58, 2);
  {
    int HW = 58 * 58, M = 160 * HW;
    bn_partial<<<32 * S, 256, 0, stream>>>(Y, 32, M, HW, 1.0 / HW, psum, psq, S);
    bn_finalize<<<1, 64, 0, stream>>>(psum, psq, g2, b2, scale, shift, 32, S,
                                      1.0 / (double)M);
  }
  {
    int total = BATCH * 32 * 29 * 29;
    plif_pool<<<(total + 255) / 256, 256, 0, stream>>>(
        Y, scale, shift, wl2, P, 32, 58, 58, 29, 29, (long)BATCH * 32 * 58 * 58);
  }

  // ---- block 3: conv3 (160,32,29,29) -> y3 (160,32,25,25) ----
  conv5_tiled<32><<<dim3(1, 32, 160), dim3(32, 8), 0, stream>>>(
      P, wc3, Y, 29, 29, 25, 25, 1);
  {
    int HW = 25 * 25, M = 160 * HW;
    bn_partial<<<32 * S, 256, 0, stream>>>(Y, 32, M, HW, 1.0 / HW, psum, psq, S);
    bn_finalize<<<1, 64, 0, stream>>>(psum, psq, g3, b3, scale, shift, 32, S,
                                      1.0 / (double)M);
  }
  {
    int total = BATCH * 32 * 12 * 12;
    plif_pool<<<(total + 255) / 256, 256, 0, stream>>>(
        Y, scale, shift, wl3, P, 32, 25, 25, 12, 12, (long)BATCH * 32 * 25 * 25);
  }

  // ---- block 4: conv4 (160,32,12,12) -> y4 (160,64,8,8) ----
  {
    int total = 160 * 64 * 8 * 8;
    conv5_simple<<<(total + 255) / 256, 256, 0, stream>>>(
        P, wc4, Y, 160, 32, 64, 12, 12, 8, 8);
  }
  {
    int HW = 8 * 8, M = 160 * HW;
    bn_partial<<<64 * S, 256, 0, stream>>>(Y, 64, M, HW, 1.0 / HW, psum, psq, S);
    bn_finalize<<<1, 64, 0, stream>>>(psum, psq, g4, b4, scale, shift, 64, S,
                                      1.0 / (double)M);
  }
  {
    int total = BATCH * 64 * 4 * 4;
    plif_pool<<<(total + 255) / 256, 256, 0, stream>>>(
        Y, scale, shift, wl4, P, 64, 8, 8, 4, 4, (long)BATCH * 64 * 8 * 8);
  }

  // ---- FC head ----
  // p4 in P is (160, 1024) with feature order c*16+h*4+w (matches reshape)
  float* h1 = Y;             // (160,1024)
  float* s1 = P;             // (160,1024) spike seq (p4 dead after fc1)
  float* h2 = Y + 163840;    // (160,10)
  fc_kernel<<<160 * 4, 256, 0, stream>>>(P, fc1w, h1, 1024, 1024, 4);
  plif_fc<<<(BATCH * 1024 + 255) / 256, 256, 0, stream>>>(h1, fc1b, wl5, s1,
                                                          1024);
  fc_kernel<<<160 * 1, 256, 0, stream>>>(s1, fc2w, h2, 1024, 10, 1);
  plif_mean<<<(BATCH * 10 + 255) / 256, 256, 0, stream>>>(h2, fc2b, wl6, out,
                                                          10);
}